// Round 1
// baseline (138.245 us; speedup 1.0000x reference)
//
#include <hip/hip_runtime.h>
#include <hip/hip_bf16.h>
#include <cstdint>
#include <cstddef>

typedef __bf16 bf16;
typedef __bf16 bf16x8 __attribute__((ext_vector_type(8)));
typedef float f32x4 __attribute__((ext_vector_type(4)));

static constexpr int NB = 4;       // batch
static constexpr int S  = 8192;
static constexpr int D  = 512;
static constexpr int H  = 512;
static constexpr int M  = NB * S;  // 32768
static constexpr int CH = 64;      // scan chunk length
static constexpr int NC = S / CH;  // 128 chunks per sequence

#define BM 128
#define BN 128
#define BK 64

// async global->LDS, 16B per lane. LDS dest must be wave-uniform base;
// lane l lands at base + l*16.
__device__ __forceinline__ void ld_lds16(void* lds, const void* g) {
  __builtin_amdgcn_global_load_lds(
      (const __attribute__((address_space(1))) uint32_t*)g,
      (__attribute__((address_space(3))) uint32_t*)lds, 16, 0, 0);
}

__global__ void cvt_bf16_kernel(const float* __restrict__ src,
                                bf16* __restrict__ dst, int n) {
  int i0 = (blockIdx.x * blockDim.x + threadIdx.x) * 8;
  int stride = gridDim.x * blockDim.x * 8;
  for (int i = i0; i + 7 < n; i += stride) {
    const float4 f0 = *(const float4*)(src + i);
    const float4 f1 = *(const float4*)(src + i + 4);
    bf16x8 o;
    o[0] = (bf16)f0.x; o[1] = (bf16)f0.y; o[2] = (bf16)f0.z; o[3] = (bf16)f0.w;
    o[4] = (bf16)f1.x; o[5] = (bf16)f1.y; o[6] = (bf16)f1.z; o[7] = (bf16)f1.w;
    *(bf16x8*)(dst + i) = o;
  }
}

// Fused dual-GEMM + gate math.
// C_z[m][n] = sum_k X[m][k] * Wz[n][k]; C_h likewise (both B^T layout).
// Epilogue: z = sigmoid(C_z + bz), ht = tanh(C_h + bh),
//           Aout = clip(1-z, eps, 1-eps), Bout = z*ht.
__global__ __launch_bounds__(256, 2)
void gemm_gates(const bf16* __restrict__ Xb,
                const bf16* __restrict__ Wzb,
                const bf16* __restrict__ Whb,
                const float* __restrict__ bz,
                const float* __restrict__ bh,
                float* __restrict__ Aout,
                float* __restrict__ Bout) {
  __shared__ __attribute__((aligned(16))) bf16 As[BM * BK];
  __shared__ __attribute__((aligned(16))) bf16 Zs[BN * BK];
  __shared__ __attribute__((aligned(16))) bf16 Hs[BN * BK];

  // consecutive blocks share the same A-panel (n-tile fastest) for L2 reuse
  const int mt = blockIdx.x >> 2;
  const int nt = blockIdx.x & 3;
  const int m0 = mt * BM;
  const int n0 = nt * BN;
  const int tid = threadIdx.x;
  const int wave = tid >> 6;
  const int lane = tid & 63;
  const int wr = wave >> 1;   // 2x2 wave grid, each wave owns 64x64
  const int wc = wave & 1;
  const int lr = lane & 15;   // row (A) / col (B) within 16x16 frag
  const int lk = lane >> 4;   // k-octet group

  f32x4 accz[4][4], acch[4][4];
  const f32x4 vzero = {0.f, 0.f, 0.f, 0.f};
#pragma unroll
  for (int i = 0; i < 4; ++i)
#pragma unroll
    for (int j = 0; j < 4; ++j) { accz[i][j] = vzero; acch[i][j] = vzero; }

  for (int ks = 0; ks < D / BK; ++ks) {
    // stage A (128x64), Wz-tile, Wh-tile: each 1024 chunks of 16B
#pragma unroll
    for (int it = 0; it < 4; ++it) {
      const int fb = it * 256 + wave * 64;  // wave-uniform flat base
      const int f  = fb + lane;
      const int row = f >> 3;
      const int kc  = f & 7;
      const size_t gk = (size_t)ks * BK + kc * 8;
      ld_lds16(&As[(size_t)fb * 8], Xb  + (size_t)(m0 + row) * D + gk);
      ld_lds16(&Zs[(size_t)fb * 8], Wzb + (size_t)(n0 + row) * D + gk);
      ld_lds16(&Hs[(size_t)fb * 8], Whb + (size_t)(n0 + row) * D + gk);
    }
    __syncthreads();
#pragma unroll
    for (int kk = 0; kk < 2; ++kk) {
      bf16x8 af[4], zf[4], hf[4];
#pragma unroll
      for (int m = 0; m < 4; ++m)
        af[m] = *(const bf16x8*)&As[(wr * 64 + m * 16 + lr) * BK + kk * 32 + lk * 8];
#pragma unroll
      for (int n = 0; n < 4; ++n) {
        const int c = (wc * 64 + n * 16 + lr) * BK + kk * 32 + lk * 8;
        zf[n] = *(const bf16x8*)&Zs[c];
        hf[n] = *(const bf16x8*)&Hs[c];
      }
#pragma unroll
      for (int m = 0; m < 4; ++m)
#pragma unroll
        for (int n = 0; n < 4; ++n) {
          accz[m][n] = __builtin_amdgcn_mfma_f32_16x16x32_bf16(af[m], zf[n], accz[m][n], 0, 0, 0);
          acch[m][n] = __builtin_amdgcn_mfma_f32_16x16x32_bf16(af[m], hf[n], acch[m][n], 0, 0, 0);
        }
    }
    __syncthreads();
  }

  // epilogue: C/D layout col = lane&15, row = (lane>>4)*4 + reg
#pragma unroll
  for (int m = 0; m < 4; ++m) {
#pragma unroll
    for (int n = 0; n < 4; ++n) {
      const int gn = n0 + wc * 64 + n * 16 + lr;
      const float bzv = bz[gn];
      const float bhv = bh[gn];
#pragma unroll
      for (int j = 0; j < 4; ++j) {
        const int gm = m0 + wr * 64 + m * 16 + lk * 4 + j;
        const float vz = accz[m][n][j] + bzv;
        const float vh = acch[m][n][j] + bhv;
        const float z = 1.f / (1.f + __expf(-vz));
        const float e = __expf(-2.f * fabsf(vh));
        float th = (1.f - e) / (1.f + e);
        th = (vh < 0.f) ? -th : th;
        float a = 1.f - z;
        a = fminf(fmaxf(a, 1e-8f), 1.f - 1e-8f);
        const size_t off = (size_t)gm * H + gn;
        Aout[off] = a;
        Bout[off] = z * th;
      }
    }
  }
}

// Pass 1: per (batch, chunk, channel) compose the chunk's affine map.
__global__ __launch_bounds__(512)
void scan_chunks(const float* __restrict__ Acoef, const float* __restrict__ Bval,
                 float* __restrict__ cA, float* __restrict__ cB) {
  const int blk = blockIdx.x;       // b*NC + c
  const int b = blk / NC, c = blk % NC;
  const int h = threadIdx.x;
  const size_t base = ((size_t)b * S + (size_t)c * CH) * H + h;
  float Ar = 1.f, Br = 0.f;
#pragma unroll 4
  for (int t = 0; t < CH; ++t) {
    const size_t off = base + (size_t)t * H;
    const float a = Acoef[off];
    const float v = Bval[off];
    Ar = a * Ar;
    Br = a * Br + v;
  }
  const size_t so = ((size_t)b * NC + c) * H + h;
  cA[so] = Ar;
  cB[so] = Br;
}

// Pass 2: sequential exclusive scan over chunk summaries per channel.
__global__ void scan_summary(const float* __restrict__ cA,
                             const float* __restrict__ cB,
                             float* __restrict__ pref) {
  const int idx = blockIdx.x * blockDim.x + threadIdx.x;  // b*H + h
  if (idx >= NB * H) return;
  const int b = idx / H, h = idx % H;
  float p = 0.f;
  for (int c = 0; c < NC; ++c) {
    const size_t so = ((size_t)b * NC + c) * H + h;
    pref[so] = p;
    p = cA[so] * p + cB[so];
  }
}

// Pass 3: re-run local scan with chunk prefix, write h over Bval (in place).
__global__ __launch_bounds__(512)
void scan_apply(const float* __restrict__ Acoef, float* __restrict__ out,
                const float* __restrict__ pref) {
  const int blk = blockIdx.x;
  const int b = blk / NC, c = blk % NC;
  const int h = threadIdx.x;
  const size_t base = ((size_t)b * S + (size_t)c * CH) * H + h;
  float hcur = pref[((size_t)b * NC + c) * H + h];
#pragma unroll 4
  for (int t = 0; t < CH; ++t) {
    const size_t off = base + (size_t)t * H;
    hcur = Acoef[off] * hcur + out[off];
    out[off] = hcur;
  }
}

extern "C" void kernel_launch(void* const* d_in, const int* in_sizes, int n_in,
                              void* d_out, int out_size, void* d_ws, size_t ws_size,
                              hipStream_t stream) {
  const float* x  = (const float*)d_in[0];
  const float* Wz = (const float*)d_in[1];
  const float* bz = (const float*)d_in[2];
  const float* Wh = (const float*)d_in[3];
  const float* bh = (const float*)d_in[4];
  float* out = (float*)d_out;

  char* ws = (char*)d_ws;
  float* Aout = (float*)ws;                        // M*H f32   = 64 MB
  bf16*  Xb   = (bf16*)(ws + (size_t)67108864);    // M*D bf16  = 32 MB
  bf16*  Wzb  = (bf16*)(ws + (size_t)100663296);   // H*D bf16  = 0.5 MB
  bf16*  Whb  = (bf16*)(ws + (size_t)101187584);   // H*D bf16  = 0.5 MB
  float* cA   = (float*)(ws + (size_t)101711872);  // NB*NC*H   = 1 MB
  float* cB   = (float*)(ws + (size_t)102760448);  // 1 MB
  float* pref = (float*)(ws + (size_t)103809024);  // 1 MB

  cvt_bf16_kernel<<<2048, 256, 0, stream>>>(x, Xb, M * D);
  cvt_bf16_kernel<<<128, 256, 0, stream>>>(Wz, Wzb, H * D);
  cvt_bf16_kernel<<<128, 256, 0, stream>>>(Wh, Whb, H * D);
  gemm_gates<<<(M / BM) * (H / BN), 256, 0, stream>>>(Xb, Wzb, Whb, bz, bh, Aout, out);
  scan_chunks<<<NB * NC, H, 0, stream>>>(Aout, out, cA, cB);
  scan_summary<<<(NB * H + 255) / 256, 256, 0, stream>>>(cA, cB, pref);
  scan_apply<<<NB * NC, H, 0, stream>>>(Aout, out, pref);
}